// Round 2
// baseline (15513.113 us; speedup 1.0000x reference)
//
#include <hip/hip_runtime.h>
#include <math.h>

// LSTM encoder: B=32, S=512, E=512, H=1024, G=4H=4096.
// Phase A: x_gates[(t)*32+b][g] = emb[src[b][t]] . Wih[:,g] + bih[g] + bhh[g]   (tiled f32 GEMM)
// Phase R: persistent cooperative kernel, 256 WGs x 512 thr, 1 WG/CU.
//   WG w owns hidden J0=w*4..w*4+3 (16 gate cols), W_hh slice (64KB) in LDS,
//   c-state in registers, h double-buffered in ws, grid barrier per step.

#define B_ 32
#define S_ 512
#define E_ 512
#define H_ 1024
#define G_ 4096
#define NWG 256
#define RTHR 512
// dynamic LDS for lstm_persistent: Wl[16][1028] + red[16*545]
#define SMEM_R (16 * 1028 * 4 + 16 * 545 * 4)   // 65792 + 34880 = 100672 B

__device__ __forceinline__ float sigmoidf_(float x) {
  return 1.0f / (1.0f + __expf(-x));
}

__device__ __forceinline__ float dot4_(float4 a, float4 b, float s) {
  return fmaf(a.x, b.x, fmaf(a.y, b.y, fmaf(a.z, b.z, fmaf(a.w, b.w, s))));
}

// ---------------- Phase A: x-gates GEMM (chunk of nt timesteps) ----------------
__global__ __launch_bounds__(256) void xgates_gemm(
    const int* __restrict__ src, const float* __restrict__ emb,
    const float* __restrict__ Wih, const float* __restrict__ bih,
    const float* __restrict__ bhh, float* __restrict__ xg, int t0)
{
  __shared__ float As[16][132];   // A transposed: As[k][row], pad 132 for banks
  __shared__ float Bs[16][132];
  __shared__ int rowOff[128];

  const int tid = threadIdx.x;
  const int row0 = blockIdx.y * 128;   // local row within chunk; r = (t-t0)*32 + b
  const int col0 = blockIdx.x * 128;

  if (tid < 128) {
    int r = row0 + tid;
    int t = t0 + (r >> 5);
    int b = r & 31;
    rowOff[tid] = src[b * S_ + t];
  }
  __syncthreads();

  const int tx = tid & 15, ty = tid >> 4;
  float acc[8][8];
#pragma unroll
  for (int i = 0; i < 8; ++i)
#pragma unroll
    for (int j = 0; j < 8; ++j) acc[i][j] = 0.f;

  const int arl = tid >> 2;        // 0..63 (A row within pass)
  const int akq = (tid & 3) * 4;   // 0,4,8,12 (A k-offset)
  const int bkr = tid >> 4;        // 0..15 (B k-row)
  const int bc  = (tid & 15) * 4;  // 0..60 (B col within pass)

  for (int k0 = 0; k0 < E_; k0 += 16) {
#pragma unroll
    for (int p = 0; p < 2; ++p) {   // A: 128 rows x 16 k (gathered)
      int rl = arl + p * 64;
      float4 v = *(const float4*)(emb + (size_t)rowOff[rl] * E_ + k0 + akq);
      As[akq + 0][rl] = v.x;
      As[akq + 1][rl] = v.y;
      As[akq + 2][rl] = v.z;
      As[akq + 3][rl] = v.w;
    }
#pragma unroll
    for (int p = 0; p < 2; ++p) {   // B: 16 k x 128 cols
      int c = bc + p * 64;
      *(float4*)&Bs[bkr][c] =
          *(const float4*)(Wih + (size_t)(k0 + bkr) * G_ + col0 + c);
    }
    __syncthreads();
#pragma unroll
    for (int k = 0; k < 16; ++k) {
      float av[8], bv[8];
      *(float4*)&av[0] = *(const float4*)&As[k][ty * 8];
      *(float4*)&av[4] = *(const float4*)&As[k][ty * 8 + 4];
      *(float4*)&bv[0] = *(const float4*)&Bs[k][tx * 4];
      *(float4*)&bv[4] = *(const float4*)&Bs[k][tx * 4 + 64];
#pragma unroll
      for (int i = 0; i < 8; ++i)
#pragma unroll
        for (int j = 0; j < 8; ++j) acc[i][j] = fmaf(av[i], bv[j], acc[i][j]);
    }
    __syncthreads();
  }

  const int ca = col0 + tx * 4;
  const int cb = ca + 64;
  float4 b1 = *(const float4*)(bih + ca);
  float4 b2 = *(const float4*)(bhh + ca);
  float4 b3 = *(const float4*)(bih + cb);
  float4 b4 = *(const float4*)(bhh + cb);
  float4 biasA = make_float4(b1.x + b2.x, b1.y + b2.y, b1.z + b2.z, b1.w + b2.w);
  float4 biasB = make_float4(b3.x + b4.x, b3.y + b4.y, b3.z + b4.z, b3.w + b4.w);
#pragma unroll
  for (int i = 0; i < 8; ++i) {
    int r = row0 + ty * 8 + i;
    float* dst = xg + (size_t)r * G_;
    *(float4*)(dst + ca) = make_float4(acc[i][0] + biasA.x, acc[i][1] + biasA.y,
                                       acc[i][2] + biasA.z, acc[i][3] + biasA.w);
    *(float4*)(dst + cb) = make_float4(acc[i][4] + biasB.x, acc[i][5] + biasB.y,
                                       acc[i][6] + biasB.z, acc[i][7] + biasB.w);
  }
}

// ---------------- Phase R: persistent recurrent kernel ----------------
__global__ __launch_bounds__(RTHR) void lstm_persistent(
    const float* __restrict__ Whh, const float* __restrict__ xg,
    float* hbuf, float* cbuf, unsigned* cnt, float* out, int t0, int nt)
{
  extern __shared__ char smem_raw[];
  float (*Wl)[1028] = (float (*)[1028])smem_raw;        // [c=16][k=1024]+pad
  float* red = (float*)(smem_raw + 16 * 1028 * 4);      // [ks=16][b*17+c], stride 545

  const int wg = blockIdx.x;
  const int tid = threadIdx.x;
  const int J0 = wg * 4;

  // Stage W_hh slice: Wl[c][k] = Whh[k][ (c>>2)*H + J0 + (c&3) ]  (one-time)
  for (int i = tid; i < 16 * H_; i += RTHR) {
    int c = i & 15;
    int k = i >> 4;
    Wl[c][k] = Whh[(size_t)k * G_ + (c >> 2) * H_ + J0 + (c & 3)];
  }

  // GEMM thread mapping: 512 thr = 8 waves x (2 kk x 8 bg x 4 cg)
  const int wave = tid >> 6;
  const int lane = tid & 63;
  const int kk = lane >> 5;             // interleaved K split within wave
  const int rem = lane & 31;
  const int bg4 = (rem >> 2) * 4;       // batch group base (4 batches)
  const int cg4 = (rem & 3) * 4;        // col group base (4 cols)
  const int ksid = wave * 2 + kk;       // 0..15 partial id
  const int Kbase = wave * 128 + kk * 4;

  // epilogue threads: tid<128 owns (b=bq, local hidden jq)
  const int bq = tid >> 2, jq = tid & 3;
  float cstate = 0.f;
  if (tid < 128) cstate = cbuf[(size_t)bq * H_ + J0 + jq];
  __syncthreads();

  for (int t = t0; t < t0 + nt; ++t) {
    const float* hrd = hbuf + (size_t)(t & 1) * (B_ * H_);
    float* hwr = hbuf + (size_t)((t + 1) & 1) * (B_ * H_);

    // prefetch this step's x-gates (hidden under the GEMM)
    float xv0 = 0.f, xv1 = 0.f, xv2 = 0.f, xv3 = 0.f;
    if (tid < 128) {
      const float* xp = xg + ((size_t)(t - t0) * B_ + bq) * G_ + J0 + jq;
      xv0 = xp[0 * H_]; xv1 = xp[1 * H_]; xv2 = xp[2 * H_]; xv3 = xp[3 * H_];
    }

    float acc[4][4];
#pragma unroll
    for (int i = 0; i < 4; ++i)
#pragma unroll
      for (int j = 0; j < 4; ++j) acc[i][j] = 0.f;

#pragma unroll 4
    for (int m = 0; m < 16; ++m) {
      int k = Kbase + m * 8;
      float4 wv[4], hv[4];
#pragma unroll
      for (int j = 0; j < 4; ++j) wv[j] = *(const float4*)&Wl[cg4 + j][k];
#pragma unroll
      for (int i = 0; i < 4; ++i)
        hv[i] = *(const float4*)(hrd + (size_t)(bg4 + i) * H_ + k);
#pragma unroll
      for (int i = 0; i < 4; ++i)
#pragma unroll
        for (int j = 0; j < 4; ++j) acc[i][j] = dot4_(hv[i], wv[j], acc[i][j]);
    }

#pragma unroll
    for (int i = 0; i < 4; ++i)
#pragma unroll
      for (int j = 0; j < 4; ++j)
        red[ksid * 545 + (bg4 + i) * 17 + (cg4 + j)] = acc[i][j];
    __syncthreads();

    if (tid < 128) {
      float g0 = xv0, g1 = xv1, g2 = xv2, g3 = xv3;
#pragma unroll
      for (int ks = 0; ks < 16; ++ks) {
        const float* rp = red + ks * 545 + bq * 17;
        g0 += rp[jq];
        g1 += rp[4 + jq];
        g2 += rp[8 + jq];
        g3 += rp[12 + jq];
      }
      float ig = sigmoidf_(g0);
      float fg = sigmoidf_(g1);
      float gg = tanhf(g2);
      float og = sigmoidf_(g3);
      cstate = fg * cstate + ig * gg;
      float hval = og * tanhf(cstate);
      hwr[(size_t)bq * H_ + J0 + jq] = hval;
      out[((size_t)bq * S_ + t) * H_ + J0 + jq] = hval;
    }
    __syncthreads();   // drains WG's global stores (vmcnt(0) before s_barrier)

    // grid barrier: step-indexed counter, agent scope (cross-XCD coherent)
    if (tid == 0) {
      __threadfence();  // agent release: flush our h/out stores device-wide
      __hip_atomic_fetch_add(cnt + t, 1u, __ATOMIC_ACQ_REL, __HIP_MEMORY_SCOPE_AGENT);
      int guard = 0;
      while (__hip_atomic_load(cnt + t, __ATOMIC_ACQUIRE, __HIP_MEMORY_SCOPE_AGENT) < NWG) {
        __builtin_amdgcn_s_sleep(2);
        if (++guard > (1 << 22)) break;   // bounded: fail loud, never hang
      }
    }
    __syncthreads();
  }

  if (tid < 128) cbuf[(size_t)bq * H_ + J0 + jq] = cstate;
}

// ---------------- host ----------------
extern "C" void kernel_launch(void* const* d_in, const int* in_sizes, int n_in,
                              void* d_out, int out_size, void* d_ws, size_t ws_size,
                              hipStream_t stream) {
  const int*   src = (const int*)d_in[0];
  const float* emb = (const float*)d_in[1];
  const float* Wih = (const float*)d_in[2];
  const float* Whh = (const float*)d_in[3];
  const float* bih = (const float*)d_in[4];
  const float* bhh = (const float*)d_in[5];
  float* out = (float*)d_out;

  char* ws = (char*)d_ws;
  float* hbuf   = (float*)ws;                             // 2*32*1024*4 = 262144
  float* cbuf   = (float*)(ws + 262144);                  // 32*1024*4   = 131072
  unsigned* cnt = (unsigned*)(ws + 262144 + 131072);      // 512*4       = 2048
  const size_t stateBytes = 262144 + 131072 + 2048;       // 395264 (256-aligned)
  float* xg = (float*)(ws + stateBytes);

  // choose largest S-chunk whose x_gates buffer fits in ws
  int chunk = 0;
  const int cand[5] = {512, 256, 128, 64, 32};
  for (int ci = 0; ci < 5; ++ci) {
    size_t need = stateBytes + (size_t)cand[ci] * B_ * G_ * 4;
    if (need <= ws_size) { chunk = cand[ci]; break; }
  }
  if (chunk == 0) return;  // ws too small even for chunk=32 (fail loud)

  (void)hipMemsetAsync(ws, 0, stateBytes, stream);  // h0 = c0 = 0, counters = 0

  (void)hipFuncSetAttribute((const void*)lstm_persistent,
                            hipFuncAttributeMaxDynamicSharedMemorySize, 160 * 1024);

  for (int t0 = 0; t0 < S_; t0 += chunk) {
    dim3 ga(G_ / 128, (chunk * B_) / 128);
    xgates_gemm<<<ga, 256, 0, stream>>>(src, emb, Wih, bih, bhh, xg, t0);

    int nt = chunk;
    void* args[] = {(void*)&Whh, (void*)&xg, (void*)&hbuf, (void*)&cbuf,
                    (void*)&cnt, (void*)&out, (void*)&t0, (void*)&nt};
    (void)hipLaunchCooperativeKernel((void*)lstm_persistent, dim3(NWG), dim3(RTHR),
                                     args, (unsigned)SMEM_R, stream);
  }
}

// Round 3
// 12008.974 us; speedup vs baseline: 1.2918x; 1.2918x over previous
//
#include <hip/hip_runtime.h>
#include <math.h>

// LSTM encoder: B=32, S=512, E=512, H=1024, G=4H=4096.
// Phase A: x_gates[(t)*32+b][g] = emb[src[b][t]] . Wih[:,g] + bih[g] + bhh[g]   (tiled f32 GEMM)
// Phase R: persistent cooperative kernel, 256 WGs x 512 thr, 1 WG/CU.
//   WG w owns hidden J0=w*4..w*4+3 (16 gate cols), W_hh slice (64KB) in LDS,
//   c-state in registers, h double-buffered in ws, grid barrier per step.
// Round 3 change: barrier rewritten — RELEASE arrival, RELAXED polling, ONE
// acquire fence after exit. (Old version did agent-ACQUIRE per poll iteration
// -> buffer_inv/L2-invalidate storm -> 116 GB/s refetch, VALUBusy 10%.)

#define B_ 32
#define S_ 512
#define E_ 512
#define H_ 1024
#define G_ 4096
#define NWG 256
#define RTHR 512
// dynamic LDS for lstm_persistent: Wl[16][1028] + red[16*545]
#define SMEM_R (16 * 1028 * 4 + 16 * 545 * 4)   // 65792 + 34880 = 100672 B

__device__ __forceinline__ float sigmoidf_(float x) {
  return 1.0f / (1.0f + __expf(-x));
}
// tanh via exp2-based fast exp; exact at +-inf saturation.
__device__ __forceinline__ float tanhf_(float x) {
  return 1.0f - 2.0f / (__expf(2.0f * x) + 1.0f);
}

__device__ __forceinline__ float dot4_(float4 a, float4 b, float s) {
  return fmaf(a.x, b.x, fmaf(a.y, b.y, fmaf(a.z, b.z, fmaf(a.w, b.w, s))));
}

// ---------------- Phase A: x-gates GEMM (chunk of nt timesteps) ----------------
__global__ __launch_bounds__(256) void xgates_gemm(
    const int* __restrict__ src, const float* __restrict__ emb,
    const float* __restrict__ Wih, const float* __restrict__ bih,
    const float* __restrict__ bhh, float* __restrict__ xg, int t0)
{
  __shared__ float As[16][132];   // A transposed: As[k][row], pad 132 for banks
  __shared__ float Bs[16][132];
  __shared__ int rowOff[128];

  const int tid = threadIdx.x;
  const int row0 = blockIdx.y * 128;   // local row within chunk; r = (t-t0)*32 + b
  const int col0 = blockIdx.x * 128;

  if (tid < 128) {
    int r = row0 + tid;
    int t = t0 + (r >> 5);
    int b = r & 31;
    rowOff[tid] = src[b * S_ + t];
  }
  __syncthreads();

  const int tx = tid & 15, ty = tid >> 4;
  float acc[8][8];
#pragma unroll
  for (int i = 0; i < 8; ++i)
#pragma unroll
    for (int j = 0; j < 8; ++j) acc[i][j] = 0.f;

  const int arl = tid >> 2;        // 0..63 (A row within pass)
  const int akq = (tid & 3) * 4;   // 0,4,8,12 (A k-offset)
  const int bkr = tid >> 4;        // 0..15 (B k-row)
  const int bc  = (tid & 15) * 4;  // 0..60 (B col within pass)

  for (int k0 = 0; k0 < E_; k0 += 16) {
#pragma unroll
    for (int p = 0; p < 2; ++p) {   // A: 128 rows x 16 k (gathered)
      int rl = arl + p * 64;
      float4 v = *(const float4*)(emb + (size_t)rowOff[rl] * E_ + k0 + akq);
      As[akq + 0][rl] = v.x;
      As[akq + 1][rl] = v.y;
      As[akq + 2][rl] = v.z;
      As[akq + 3][rl] = v.w;
    }
#pragma unroll
    for (int p = 0; p < 2; ++p) {   // B: 16 k x 128 cols
      int c = bc + p * 64;
      *(float4*)&Bs[bkr][c] =
          *(const float4*)(Wih + (size_t)(k0 + bkr) * G_ + col0 + c);
    }
    __syncthreads();
#pragma unroll
    for (int k = 0; k < 16; ++k) {
      float av[8], bv[8];
      *(float4*)&av[0] = *(const float4*)&As[k][ty * 8];
      *(float4*)&av[4] = *(const float4*)&As[k][ty * 8 + 4];
      *(float4*)&bv[0] = *(const float4*)&Bs[k][tx * 4];
      *(float4*)&bv[4] = *(const float4*)&Bs[k][tx * 4 + 64];
#pragma unroll
      for (int i = 0; i < 8; ++i)
#pragma unroll
        for (int j = 0; j < 8; ++j) acc[i][j] = fmaf(av[i], bv[j], acc[i][j]);
    }
    __syncthreads();
  }

  const int ca = col0 + tx * 4;
  const int cb = ca + 64;
  float4 b1 = *(const float4*)(bih + ca);
  float4 b2 = *(const float4*)(bhh + ca);
  float4 b3 = *(const float4*)(bih + cb);
  float4 b4 = *(const float4*)(bhh + cb);
  float4 biasA = make_float4(b1.x + b2.x, b1.y + b2.y, b1.z + b2.z, b1.w + b2.w);
  float4 biasB = make_float4(b3.x + b4.x, b3.y + b4.y, b3.z + b4.z, b3.w + b4.w);
#pragma unroll
  for (int i = 0; i < 8; ++i) {
    int r = row0 + ty * 8 + i;
    float* dst = xg + (size_t)r * G_;
    *(float4*)(dst + ca) = make_float4(acc[i][0] + biasA.x, acc[i][1] + biasA.y,
                                       acc[i][2] + biasA.z, acc[i][3] + biasA.w);
    *(float4*)(dst + cb) = make_float4(acc[i][4] + biasB.x, acc[i][5] + biasB.y,
                                       acc[i][6] + biasB.z, acc[i][7] + biasB.w);
  }
}

// ---------------- Phase R: persistent recurrent kernel ----------------
__global__ __launch_bounds__(RTHR) void lstm_persistent(
    const float* __restrict__ Whh, const float* __restrict__ xg,
    float* hbuf, float* cbuf, unsigned* cnt, float* out, int t0, int nt)
{
  extern __shared__ char smem_raw[];
  float (*Wl)[1028] = (float (*)[1028])smem_raw;        // [c=16][k=1024]+pad
  float* red = (float*)(smem_raw + 16 * 1028 * 4);      // [ks=16][b*17+c], stride 545

  const int wg = blockIdx.x;
  const int tid = threadIdx.x;
  const int J0 = wg * 4;

  // Stage W_hh slice: Wl[c][k] = Whh[k][ (c>>2)*H + J0 + (c&3) ]  (one-time)
  for (int i = tid; i < 16 * H_; i += RTHR) {
    int c = i & 15;
    int k = i >> 4;
    Wl[c][k] = Whh[(size_t)k * G_ + (c >> 2) * H_ + J0 + (c & 3)];
  }

  // GEMM thread mapping: 512 thr = 8 waves x (2 kk x 8 bg x 4 cg)
  const int wave = tid >> 6;
  const int lane = tid & 63;
  const int kk = lane >> 5;             // interleaved K split within wave
  const int rem = lane & 31;
  const int bg4 = (rem >> 2) * 4;       // batch group base (4 batches)
  const int cg4 = (rem & 3) * 4;        // col group base (4 cols)
  const int ksid = wave * 2 + kk;       // 0..15 partial id
  const int Kbase = wave * 128 + kk * 4;

  // epilogue threads: tid<128 owns (b=bq, local hidden jq)
  const int bq = tid >> 2, jq = tid & 3;
  float cstate = 0.f;
  if (tid < 128) cstate = cbuf[(size_t)bq * H_ + J0 + jq];
  __syncthreads();

  for (int t = t0; t < t0 + nt; ++t) {
    const float* hrd = hbuf + (size_t)(t & 1) * (B_ * H_);
    float* hwr = hbuf + (size_t)((t + 1) & 1) * (B_ * H_);

    // prefetch this step's x-gates (hidden under the GEMM)
    float xv0 = 0.f, xv1 = 0.f, xv2 = 0.f, xv3 = 0.f;
    if (tid < 128) {
      const float* xp = xg + ((size_t)(t - t0) * B_ + bq) * G_ + J0 + jq;
      xv0 = xp[0 * H_]; xv1 = xp[1 * H_]; xv2 = xp[2 * H_]; xv3 = xp[3 * H_];
    }

    float acc[4][4];
#pragma unroll
    for (int i = 0; i < 4; ++i)
#pragma unroll
      for (int j = 0; j < 4; ++j) acc[i][j] = 0.f;

#pragma unroll 4
    for (int m = 0; m < 16; ++m) {
      int k = Kbase + m * 8;
      float4 wv[4], hv[4];
#pragma unroll
      for (int j = 0; j < 4; ++j) wv[j] = *(const float4*)&Wl[cg4 + j][k];
#pragma unroll
      for (int i = 0; i < 4; ++i)
        hv[i] = *(const float4*)(hrd + (size_t)(bg4 + i) * H_ + k);
#pragma unroll
      for (int i = 0; i < 4; ++i)
#pragma unroll
        for (int j = 0; j < 4; ++j) acc[i][j] = dot4_(hv[i], wv[j], acc[i][j]);
    }

#pragma unroll
    for (int i = 0; i < 4; ++i)
#pragma unroll
      for (int j = 0; j < 4; ++j)
        red[ksid * 545 + (bg4 + i) * 17 + (cg4 + j)] = acc[i][j];
    __syncthreads();

    if (tid < 128) {
      float g0 = xv0, g1 = xv1, g2 = xv2, g3 = xv3;
#pragma unroll
      for (int ks = 0; ks < 16; ++ks) {
        const float* rp = red + ks * 545 + bq * 17;
        g0 += rp[jq];
        g1 += rp[4 + jq];
        g2 += rp[8 + jq];
        g3 += rp[12 + jq];
      }
      float ig = sigmoidf_(g0);
      float fg = sigmoidf_(g1);
      float gg = tanhf_(g2);
      float og = sigmoidf_(g3);
      cstate = fg * cstate + ig * gg;
      float hval = og * tanhf_(cstate);
      hwr[(size_t)bq * H_ + J0 + jq] = hval;
      out[((size_t)bq * S_ + t) * H_ + J0 + jq] = hval;
    }
    __syncthreads();   // all waves drain vmcnt before s_barrier -> h stores in L2

    // grid barrier: RELEASE arrival (one L2 writeback), RELAXED polling
    // (cache-bypassing loads, no invalidate), ONE acquire fence on exit.
    if (tid == 0) {
      __hip_atomic_fetch_add(cnt + t, 1u, __ATOMIC_RELEASE, __HIP_MEMORY_SCOPE_AGENT);
      int guard = 0;
      while (__hip_atomic_load(cnt + t, __ATOMIC_RELAXED, __HIP_MEMORY_SCOPE_AGENT) < NWG) {
        __builtin_amdgcn_s_sleep(1);
        if (++guard > (1 << 22)) break;   // bounded: fail loud, never hang
      }
      __builtin_amdgcn_fence(__ATOMIC_ACQUIRE, "agent");  // drop stale h lines once
    }
    __syncthreads();
  }

  if (tid < 128) cbuf[(size_t)bq * H_ + J0 + jq] = cstate;
}

// ---------------- host ----------------
extern "C" void kernel_launch(void* const* d_in, const int* in_sizes, int n_in,
                              void* d_out, int out_size, void* d_ws, size_t ws_size,
                              hipStream_t stream) {
  const int*   src = (const int*)d_in[0];
  const float* emb = (const float*)d_in[1];
  const float* Wih = (const float*)d_in[2];
  const float* Whh = (const float*)d_in[3];
  const float* bih = (const float*)d_in[4];
  const float* bhh = (const float*)d_in[5];
  float* out = (float*)d_out;

  char* ws = (char*)d_ws;
  float* hbuf   = (float*)ws;                             // 2*32*1024*4 = 262144
  float* cbuf   = (float*)(ws + 262144);                  // 32*1024*4   = 131072
  unsigned* cnt = (unsigned*)(ws + 262144 + 131072);      // 512*4       = 2048
  const size_t stateBytes = 262144 + 131072 + 2048;       // 395264 (256-aligned)
  float* xg = (float*)(ws + stateBytes);

  // choose largest S-chunk whose x_gates buffer fits in ws
  int chunk = 0;
  const int cand[5] = {512, 256, 128, 64, 32};
  for (int ci = 0; ci < 5; ++ci) {
    size_t need = stateBytes + (size_t)cand[ci] * B_ * G_ * 4;
    if (need <= ws_size) { chunk = cand[ci]; break; }
  }
  if (chunk == 0) return;  // ws too small even for chunk=32 (fail loud)

  (void)hipMemsetAsync(ws, 0, stateBytes, stream);  // h0 = c0 = 0, counters = 0

  (void)hipFuncSetAttribute((const void*)lstm_persistent,
                            hipFuncAttributeMaxDynamicSharedMemorySize, 160 * 1024);

  for (int t0 = 0; t0 < S_; t0 += chunk) {
    dim3 ga(G_ / 128, (chunk * B_) / 128);
    xgates_gemm<<<ga, 256, 0, stream>>>(src, emb, Wih, bih, bhh, xg, t0);

    int nt = chunk;
    void* args[] = {(void*)&Whh, (void*)&xg, (void*)&hbuf, (void*)&cbuf,
                    (void*)&cnt, (void*)&out, (void*)&t0, (void*)&nt};
    (void)hipLaunchCooperativeKernel((void*)lstm_persistent, dim3(NWG), dim3(RTHR),
                                     args, (unsigned)SMEM_R, stream);
  }
}

// Round 4
// 5126.222 us; speedup vs baseline: 3.0262x; 2.3427x over previous
//
#include <hip/hip_runtime.h>
#include <math.h>

// LSTM encoder: B=32, S=512, E=512, H=1024, G=4H=4096.
// Phase A: x_gates GEMM (unchanged from round 3 — not the bottleneck).
// Phase R: persistent cooperative kernel, 256 WGs x 512 thr, 1 WG/CU.
// Round 4: ZERO cache-maintenance coherence scheme:
//   - h ring buffer (first-touch reads -> no L2 invalidation needed)
//   - h writes via relaxed agent-scope atomic stores (write-through to MALL)
//   - all-relaxed two-level tree barrier (no release/acquire fences at all)
//   - XCD-aware J0 swizzle: WGs sharing 64B xg/out/h lines are on one XCD

#define B_ 32
#define S_ 512
#define E_ 512
#define H_ 1024
#define G_ 4096
#define NWG 256
#define RTHR 512
#define BH_ (B_ * H_)              // 32768 floats = 131072 B per h slot
// dynamic LDS for lstm_persistent: Wl[16][1028] + red[16*545]
#define SMEM_R (16 * 1028 * 4 + 16 * 545 * 4)   // 65792 + 34880 = 100672 B

__device__ __forceinline__ float sigmoidf_(float x) {
  return 1.0f / (1.0f + __expf(-x));
}
__device__ __forceinline__ float tanhf_(float x) {
  return 1.0f - 2.0f / (__expf(2.0f * x) + 1.0f);
}
__device__ __forceinline__ float dot4_(float4 a, float4 b, float s) {
  return fmaf(a.x, b.x, fmaf(a.y, b.y, fmaf(a.z, b.z, fmaf(a.w, b.w, s))));
}

// ---------------- Phase A: x-gates GEMM (chunk of nt timesteps) ----------------
__global__ __launch_bounds__(256) void xgates_gemm(
    const int* __restrict__ src, const float* __restrict__ emb,
    const float* __restrict__ Wih, const float* __restrict__ bih,
    const float* __restrict__ bhh, float* __restrict__ xg, int t0)
{
  __shared__ float As[16][132];
  __shared__ float Bs[16][132];
  __shared__ int rowOff[128];

  const int tid = threadIdx.x;
  const int row0 = blockIdx.y * 128;
  const int col0 = blockIdx.x * 128;

  if (tid < 128) {
    int r = row0 + tid;
    int t = t0 + (r >> 5);
    int b = r & 31;
    rowOff[tid] = src[b * S_ + t];
  }
  __syncthreads();

  const int tx = tid & 15, ty = tid >> 4;
  float acc[8][8];
#pragma unroll
  for (int i = 0; i < 8; ++i)
#pragma unroll
    for (int j = 0; j < 8; ++j) acc[i][j] = 0.f;

  const int arl = tid >> 2;
  const int akq = (tid & 3) * 4;
  const int bkr = tid >> 4;
  const int bc  = (tid & 15) * 4;

  for (int k0 = 0; k0 < E_; k0 += 16) {
#pragma unroll
    for (int p = 0; p < 2; ++p) {
      int rl = arl + p * 64;
      float4 v = *(const float4*)(emb + (size_t)rowOff[rl] * E_ + k0 + akq);
      As[akq + 0][rl] = v.x;
      As[akq + 1][rl] = v.y;
      As[akq + 2][rl] = v.z;
      As[akq + 3][rl] = v.w;
    }
#pragma unroll
    for (int p = 0; p < 2; ++p) {
      int c = bc + p * 64;
      *(float4*)&Bs[bkr][c] =
          *(const float4*)(Wih + (size_t)(k0 + bkr) * G_ + col0 + c);
    }
    __syncthreads();
#pragma unroll
    for (int k = 0; k < 16; ++k) {
      float av[8], bv[8];
      *(float4*)&av[0] = *(const float4*)&As[k][ty * 8];
      *(float4*)&av[4] = *(const float4*)&As[k][ty * 8 + 4];
      *(float4*)&bv[0] = *(const float4*)&Bs[k][tx * 4];
      *(float4*)&bv[4] = *(const float4*)&Bs[k][tx * 4 + 64];
#pragma unroll
      for (int i = 0; i < 8; ++i)
#pragma unroll
        for (int j = 0; j < 8; ++j) acc[i][j] = fmaf(av[i], bv[j], acc[i][j]);
    }
    __syncthreads();
  }

  const int ca = col0 + tx * 4;
  const int cb = ca + 64;
  float4 b1 = *(const float4*)(bih + ca);
  float4 b2 = *(const float4*)(bhh + ca);
  float4 b3 = *(const float4*)(bih + cb);
  float4 b4 = *(const float4*)(bhh + cb);
  float4 biasA = make_float4(b1.x + b2.x, b1.y + b2.y, b1.z + b2.z, b1.w + b2.w);
  float4 biasB = make_float4(b3.x + b4.x, b3.y + b4.y, b3.z + b4.z, b3.w + b4.w);
#pragma unroll
  for (int i = 0; i < 8; ++i) {
    int r = row0 + ty * 8 + i;
    float* dst = xg + (size_t)r * G_;
    *(float4*)(dst + ca) = make_float4(acc[i][0] + biasA.x, acc[i][1] + biasA.y,
                                       acc[i][2] + biasA.z, acc[i][3] + biasA.w);
    *(float4*)(dst + cb) = make_float4(acc[i][4] + biasB.x, acc[i][5] + biasB.y,
                                       acc[i][6] + biasB.z, acc[i][7] + biasB.w);
  }
}

// ---------------- Phase R: persistent recurrent kernel ----------------
__global__ __launch_bounds__(RTHR) void lstm_persistent(
    const float* __restrict__ Whh, const float* __restrict__ xg,
    float* hring, float* cbuf, unsigned* root, unsigned* grp,
    float* out, int t0, int nt)
{
  extern __shared__ char smem_raw[];
  float (*Wl)[1028] = (float (*)[1028])smem_raw;        // [c=16][k=1024]+pad
  float* red = (float*)(smem_raw + 16 * 1028 * 4);      // [ks=16][b*17+c]

  const int wg = blockIdx.x;
  const int tid = threadIdx.x;
  // XCD swizzle: WGs with the same (wg&7) share an XCD (round-robin dispatch);
  // give them contiguous hidden-unit blocks so 64B xg/out/h lines stay XCD-local.
  const int J0 = 4 * ((wg & 7) * 32 + (wg >> 3));

  // Stage W_hh slice (one-time): Wl[c][k] = Whh[k][(c>>2)*H + J0 + (c&3)]
  for (int i = tid; i < 16 * H_; i += RTHR) {
    int c = i & 15;
    int k = i >> 4;
    Wl[c][k] = Whh[(size_t)k * G_ + (c >> 2) * H_ + J0 + (c & 3)];
  }

  // GEMM thread mapping: 512 thr = 8 waves x (2 kk x 8 bg x 4 cg)
  const int wave = tid >> 6;
  const int lane = tid & 63;
  const int kk = lane >> 5;
  const int rem = lane & 31;
  const int bg4 = (rem >> 2) * 4;
  const int cg4 = (rem & 3) * 4;
  const int ksid = wave * 2 + kk;
  const int Kbase = wave * 128 + kk * 4;

  const int bq = tid >> 2, jq = tid & 3;
  float cstate = 0.f;
  if (tid < 128) cstate = cbuf[(size_t)bq * H_ + J0 + jq];
  __syncthreads();

  for (int t = t0; t < t0 + nt; ++t) {
    const int lt = t - t0;
    const float* hrd = hring + (size_t)lt * BH_;                    // first touch
    float* hwr = hring + (size_t)((lt == nt - 1) ? 0 : lt + 1) * BH_; // slot0 seeds next dispatch

    // prefetch this step's x-gates (hidden under the GEMM)
    float xv0 = 0.f, xv1 = 0.f, xv2 = 0.f, xv3 = 0.f;
    if (tid < 128) {
      const float* xp = xg + ((size_t)lt * B_ + bq) * G_ + J0 + jq;
      xv0 = xp[0 * H_]; xv1 = xp[1 * H_]; xv2 = xp[2 * H_]; xv3 = xp[3 * H_];
    }

    float acc[4][4];
#pragma unroll
    for (int i = 0; i < 4; ++i)
#pragma unroll
      for (int j = 0; j < 4; ++j) acc[i][j] = 0.f;

#pragma unroll 4
    for (int m = 0; m < 16; ++m) {
      int k = Kbase + m * 8;
      float4 wv[4], hv[4];
#pragma unroll
      for (int j = 0; j < 4; ++j) wv[j] = *(const float4*)&Wl[cg4 + j][k];
#pragma unroll
      for (int i = 0; i < 4; ++i)
        hv[i] = *(const float4*)(hrd + (size_t)(bg4 + i) * H_ + k);
#pragma unroll
      for (int i = 0; i < 4; ++i)
#pragma unroll
        for (int j = 0; j < 4; ++j) acc[i][j] = dot4_(hv[i], wv[j], acc[i][j]);
    }

#pragma unroll
    for (int i = 0; i < 4; ++i)
#pragma unroll
      for (int j = 0; j < 4; ++j)
        red[ksid * 545 + (bg4 + i) * 17 + (cg4 + j)] = acc[i][j];
    __syncthreads();

    if (tid < 128) {
      float g0 = xv0, g1 = xv1, g2 = xv2, g3 = xv3;
#pragma unroll
      for (int ks = 0; ks < 16; ++ks) {
        const float* rp = red + ks * 545 + bq * 17;
        g0 += rp[jq];
        g1 += rp[4 + jq];
        g2 += rp[8 + jq];
        g3 += rp[12 + jq];
      }
      float ig = sigmoidf_(g0);
      float fg = sigmoidf_(g1);
      float gg = tanhf_(g2);
      float og = sigmoidf_(g3);
      cstate = fg * cstate + ig * gg;
      float hval = og * tanhf_(cstate);
      // write-through to MALL (sc-flagged store): no dirty L2 line, no wbl2 needed
      __hip_atomic_store(hwr + (size_t)bq * H_ + J0 + jq, hval,
                         __ATOMIC_RELAXED, __HIP_MEMORY_SCOPE_AGENT);
      out[((size_t)bq * S_ + t) * H_ + J0 + jq] = hval;   // normal store (kernel-end flush)
    }
    __syncthreads();   // every wave drains vmcnt -> all h stores acked at MALL

    // All-relaxed two-level tree barrier. No fences: h is write-through + first-touch.
    if (tid == 0) {
      unsigned* gslot = grp + ((size_t)t * 16 + (unsigned)(wg & 15)) * 16;  // 64B-strided
      unsigned old = __hip_atomic_fetch_add(gslot, 1u, __ATOMIC_RELAXED,
                                            __HIP_MEMORY_SCOPE_AGENT);
      if (old == 15u)   // group leader promotes to root (issues after group RMW returns)
        __hip_atomic_fetch_add(root + (size_t)t * 16, 1u, __ATOMIC_RELAXED,
                               __HIP_MEMORY_SCOPE_AGENT);
      int guard = 0;
      while (__hip_atomic_load(root + (size_t)t * 16, __ATOMIC_RELAXED,
                               __HIP_MEMORY_SCOPE_AGENT) < 16u) {
        __builtin_amdgcn_s_sleep(1);
        if (++guard > (1 << 22)) break;   // bounded: fail loud, never hang
      }
    }
    __syncthreads();
  }

  if (tid < 128) cbuf[(size_t)bq * H_ + J0 + jq] = cstate;
}

// ---------------- host ----------------
extern "C" void kernel_launch(void* const* d_in, const int* in_sizes, int n_in,
                              void* d_out, int out_size, void* d_ws, size_t ws_size,
                              hipStream_t stream) {
  const int*   src = (const int*)d_in[0];
  const float* emb = (const float*)d_in[1];
  const float* Wih = (const float*)d_in[2];
  const float* Whh = (const float*)d_in[3];
  const float* bih = (const float*)d_in[4];
  const float* bhh = (const float*)d_in[5];
  float* out = (float*)d_out;

  // ws layout: [cbuf 128K][root 32K][grp 512K][hring (chunk+1)*128K][xg chunk*512K]
  char* ws = (char*)d_ws;
  float*    cbuf = (float*)ws;                       // 131072 B
  unsigned* root = (unsigned*)(ws + 131072);         // 512 * 64B = 32768 B
  unsigned* grp  = (unsigned*)(ws + 131072 + 32768); // 512*16*64B = 524288 B
  const size_t stateBytes = 131072 + 32768 + 524288; // 688128

  int chunk = 0;
  const int cand[4] = {256, 128, 64, 32};
  for (int ci = 0; ci < 4; ++ci) {
    size_t need = stateBytes + (size_t)(cand[ci] + 1) * 131072
                  + (size_t)cand[ci] * B_ * G_ * 4;
    if (need <= ws_size) { chunk = cand[ci]; break; }
  }
  if (chunk == 0) return;  // fail loud

  float* hring = (float*)(ws + stateBytes);
  float* xg    = (float*)(ws + stateBytes + (size_t)(chunk + 1) * 131072);

  (void)hipMemsetAsync(ws, 0, stateBytes, stream);    // c0 = 0, all counters = 0
  (void)hipMemsetAsync(hring, 0, 131072, stream);     // h0 = 0 (ring slot 0)

  (void)hipFuncSetAttribute((const void*)lstm_persistent,
                            hipFuncAttributeMaxDynamicSharedMemorySize, 160 * 1024);

  for (int t0 = 0; t0 < S_; t0 += chunk) {
    dim3 ga(G_ / 128, (chunk * B_) / 128);
    xgates_gemm<<<ga, 256, 0, stream>>>(src, emb, Wih, bih, bhh, xg, t0);

    int nt = chunk;
    void* args[] = {(void*)&Whh, (void*)&xg, (void*)&hring, (void*)&cbuf,
                    (void*)&root, (void*)&grp, (void*)&out, (void*)&t0, (void*)&nt};
    (void)hipLaunchCooperativeKernel((void*)lstm_persistent, dim3(NWG), dim3(RTHR),
                                     args, (unsigned)SMEM_R, stream);
  }
}

// Round 5
// 3674.910 us; speedup vs baseline: 4.2214x; 1.3949x over previous
//
#include <hip/hip_runtime.h>
#include <math.h>

// LSTM encoder: B=32, S=512, E=512, H=1024, G=4H=4096.
// Round 5: recurrent GEMM moved to f16 MFMA (16x16x32).
//   - W_hh pre-transposed+converted to f16 Wt[4096][1024] (one-time kernel)
//   - each wave holds its W fragments in 16 VGPRs permanently (no LDS W)
//   - h broadcast as f16 (64 KB total), read 1x per WG as MFMA A-fragments
//   - LDS only holds the 8-wave partial reduction (17 KB)
//   - coherence scheme from round 4 kept: first-touch h ring, write-through
//     stores, all-relaxed tree barrier, XCD-aware J0 swizzle

#define B_ 32
#define S_ 512
#define E_ 512
#define H_ 1024
#define G_ 4096
#define NWG 256
#define RTHR 512
#define BH_ (B_ * H_)

typedef _Float16 f16x8 __attribute__((ext_vector_type(8)));
typedef float f32x4 __attribute__((ext_vector_type(4)));

__device__ __forceinline__ float sigmoidf_(float x) {
  return 1.0f / (1.0f + __expf(-x));
}
__device__ __forceinline__ float tanhf_(float x) {
  return 1.0f - 2.0f / (__expf(2.0f * x) + 1.0f);
}

// ---------------- one-time: Whh f32[1024][4096] -> Wt f16[4096][1024] ----------------
__global__ __launch_bounds__(256) void wt_kernel(
    const float* __restrict__ Whh, _Float16* __restrict__ Wt)
{
  __shared__ float Lt[64][65];
  const int c0 = blockIdx.x * 64;   // 4096/64 = 64 tiles
  const int k0 = blockIdx.y * 64;   // 1024/64 = 16 tiles
  const int tid = threadIdx.x;
  const int colL = tid & 63;
  const int rq = tid >> 6;          // 0..3
#pragma unroll 4
  for (int p = 0; p < 16; ++p) {
    int r = p * 4 + rq;
    Lt[colL][r] = Whh[(size_t)(k0 + r) * G_ + c0 + colL];
  }
  __syncthreads();
  const int col = tid >> 2;
  const int kq = (tid & 3) * 16;
  _Float16 tmp[16];
#pragma unroll
  for (int i = 0; i < 16; ++i) tmp[i] = (_Float16)Lt[col][kq + i];
  *(f16x8*)(Wt + (size_t)(c0 + col) * H_ + k0 + kq)     = *(f16x8*)&tmp[0];
  *(f16x8*)(Wt + (size_t)(c0 + col) * H_ + k0 + kq + 8) = *(f16x8*)&tmp[8];
}

// ---------------- Phase A: x-gates GEMM (f32, unchanged) ----------------
__global__ __launch_bounds__(256) void xgates_gemm(
    const int* __restrict__ src, const float* __restrict__ emb,
    const float* __restrict__ Wih, const float* __restrict__ bih,
    const float* __restrict__ bhh, float* __restrict__ xg, int t0)
{
  __shared__ float As[16][132];
  __shared__ float Bs[16][132];
  __shared__ int rowOff[128];

  const int tid = threadIdx.x;
  const int row0 = blockIdx.y * 128;
  const int col0 = blockIdx.x * 128;

  if (tid < 128) {
    int r = row0 + tid;
    int t = t0 + (r >> 5);
    int b = r & 31;
    rowOff[tid] = src[b * S_ + t];
  }
  __syncthreads();

  const int tx = tid & 15, ty = tid >> 4;
  float acc[8][8];
#pragma unroll
  for (int i = 0; i < 8; ++i)
#pragma unroll
    for (int j = 0; j < 8; ++j) acc[i][j] = 0.f;

  const int arl = tid >> 2;
  const int akq = (tid & 3) * 4;
  const int bkr = tid >> 4;
  const int bc  = (tid & 15) * 4;

  for (int k0 = 0; k0 < E_; k0 += 16) {
#pragma unroll
    for (int p = 0; p < 2; ++p) {
      int rl = arl + p * 64;
      float4 v = *(const float4*)(emb + (size_t)rowOff[rl] * E_ + k0 + akq);
      As[akq + 0][rl] = v.x;
      As[akq + 1][rl] = v.y;
      As[akq + 2][rl] = v.z;
      As[akq + 3][rl] = v.w;
    }
#pragma unroll
    for (int p = 0; p < 2; ++p) {
      int c = bc + p * 64;
      *(float4*)&Bs[bkr][c] =
          *(const float4*)(Wih + (size_t)(k0 + bkr) * G_ + col0 + c);
    }
    __syncthreads();
#pragma unroll
    for (int k = 0; k < 16; ++k) {
      float av[8], bv[8];
      *(float4*)&av[0] = *(const float4*)&As[k][ty * 8];
      *(float4*)&av[4] = *(const float4*)&As[k][ty * 8 + 4];
      *(float4*)&bv[0] = *(const float4*)&Bs[k][tx * 4];
      *(float4*)&bv[4] = *(const float4*)&Bs[k][tx * 4 + 64];
#pragma unroll
      for (int i = 0; i < 8; ++i)
#pragma unroll
        for (int j = 0; j < 8; ++j) acc[i][j] = fmaf(av[i], bv[j], acc[i][j]);
    }
    __syncthreads();
  }

  const int ca = col0 + tx * 4;
  const int cb = ca + 64;
  float4 b1 = *(const float4*)(bih + ca);
  float4 b2 = *(const float4*)(bhh + ca);
  float4 b3 = *(const float4*)(bih + cb);
  float4 b4 = *(const float4*)(bhh + cb);
  float4 biasA = make_float4(b1.x + b2.x, b1.y + b2.y, b1.z + b2.z, b1.w + b2.w);
  float4 biasB = make_float4(b3.x + b4.x, b3.y + b4.y, b3.z + b4.z, b3.w + b4.w);
#pragma unroll
  for (int i = 0; i < 8; ++i) {
    int r = row0 + ty * 8 + i;
    float* dst = xg + (size_t)r * G_;
    *(float4*)(dst + ca) = make_float4(acc[i][0] + biasA.x, acc[i][1] + biasA.y,
                                       acc[i][2] + biasA.z, acc[i][3] + biasA.w);
    *(float4*)(dst + cb) = make_float4(acc[i][4] + biasB.x, acc[i][5] + biasB.y,
                                       acc[i][6] + biasB.z, acc[i][7] + biasB.w);
  }
}

// ---------------- Phase R: persistent MFMA recurrent kernel ----------------
// Per WG: D[32 b x 16 c] = h[32 x 1024] * Wslice[1024 x 16], K split 8 waves.
// Wave w: k in [w*128, w*128+128), 4 MFMA k-steps of 32, 2 M-tiles -> 8 MFMA.
__global__ __launch_bounds__(RTHR) void lstm_mfma(
    const _Float16* __restrict__ Wt, const float* __restrict__ xg,
    unsigned short* hring, float* cbuf, unsigned* root, unsigned* grp,
    float* out, int t0, int nt)
{
  __shared__ float red[8 * 32 * 17];   // [wave][b][c] stride-17: 17408 B

  const int wg = blockIdx.x;
  const int tid = threadIdx.x;
  const int J0 = 4 * ((wg & 7) * 32 + (wg >> 3));   // XCD-contiguous hidden blocks

  const int wave = tid >> 6;
  const int lane = tid & 63;
  const int lrow = lane & 15;        // A-row (M) / B-col (N) within tile
  const int lhi  = lane >> 4;        // k-group 0..3
  const int Kw   = wave * 128;
  // tile col c = lrow -> global gate column
  const int gcol = (lrow >> 2) * H_ + J0 + (lrow & 3);

  // W fragments: persistent in registers for the whole dispatch.
  // B-frag element j of k-step s: Wt[gcol][Kw + s*32 + lhi*8 + j]
  f16x8 bf[4];
#pragma unroll
  for (int s = 0; s < 4; ++s)
    bf[s] = *(const f16x8*)(Wt + (size_t)gcol * H_ + Kw + s * 32 + lhi * 8);

  const int bq = tid >> 2, jq = tid & 3;   // epilogue mapping (tid<128)
  float cstate = 0.f;
  if (tid < 128) cstate = cbuf[(size_t)bq * H_ + J0 + jq];

  for (int t = t0; t < t0 + nt; ++t) {
    const int lt = t - t0;
    const _Float16* hrd = (const _Float16*)hring + (size_t)lt * BH_;   // first touch
    unsigned short* hwr = hring + (size_t)((lt == nt - 1) ? 0 : lt + 1) * BH_;

    float xv0 = 0.f, xv1 = 0.f, xv2 = 0.f, xv3 = 0.f;
    if (tid < 128) {
      const float* xp = xg + ((size_t)lt * B_ + bq) * G_ + J0 + jq;
      xv0 = xp[0 * H_]; xv1 = xp[1 * H_]; xv2 = xp[2 * H_]; xv3 = xp[3 * H_];
    }

    f32x4 acc0 = {0.f, 0.f, 0.f, 0.f};
    f32x4 acc1 = {0.f, 0.f, 0.f, 0.f};
#pragma unroll
    for (int s = 0; s < 4; ++s) {
      // A-frag: h[b = mtile*16 + lrow][k = Kw + s*32 + lhi*8 + j]  (same k map as B)
      f16x8 a0 = *(const f16x8*)(hrd + (size_t)lrow * H_ + Kw + s * 32 + lhi * 8);
      f16x8 a1 = *(const f16x8*)(hrd + (size_t)(16 + lrow) * H_ + Kw + s * 32 + lhi * 8);
      acc0 = __builtin_amdgcn_mfma_f32_16x16x32_f16(a0, bf[s], acc0, 0, 0, 0);
      acc1 = __builtin_amdgcn_mfma_f32_16x16x32_f16(a1, bf[s], acc1, 0, 0, 0);
    }

    // D layout: col = lane&15, row(within tile) = lhi*4 + r
#pragma unroll
    for (int r = 0; r < 4; ++r) {
      red[(wave * 32 + lhi * 4 + r) * 17 + lrow]      = acc0[r];
      red[(wave * 32 + 16 + lhi * 4 + r) * 17 + lrow] = acc1[r];
    }
    __syncthreads();

    if (tid < 128) {
      float g0 = xv0, g1 = xv1, g2 = xv2, g3 = xv3;
#pragma unroll
      for (int w = 0; w < 8; ++w) {
        const float* rp = red + (w * 32 + bq) * 17;
        g0 += rp[jq];
        g1 += rp[4 + jq];
        g2 += rp[8 + jq];
        g3 += rp[12 + jq];
      }
      float ig = sigmoidf_(g0);
      float fg = sigmoidf_(g1);
      float gg = tanhf_(g2);
      float og = sigmoidf_(g3);
      cstate = fg * cstate + ig * gg;
      float hval = og * tanhf_(cstate);
      out[((size_t)bq * S_ + t) * H_ + J0 + jq] = hval;       // f32, pre-quantization
      _Float16 hf = (_Float16)hval;
      unsigned short hb;
      __builtin_memcpy(&hb, &hf, 2);
      // write-through to MALL: no dirty L2 line anywhere
      __hip_atomic_store(hwr + (size_t)bq * H_ + J0 + jq, hb,
                         __ATOMIC_RELAXED, __HIP_MEMORY_SCOPE_AGENT);
    }
    __syncthreads();   // drain all stores (vmcnt before barrier arrival)

    // all-relaxed two-level tree barrier (round-4 scheme, unchanged)
    if (tid == 0) {
      unsigned* gslot = grp + ((size_t)t * 16 + (unsigned)(wg & 15)) * 16;
      unsigned old = __hip_atomic_fetch_add(gslot, 1u, __ATOMIC_RELAXED,
                                            __HIP_MEMORY_SCOPE_AGENT);
      if (old == 15u)
        __hip_atomic_fetch_add(root + (size_t)t * 16, 1u, __ATOMIC_RELAXED,
                               __HIP_MEMORY_SCOPE_AGENT);
      int guard = 0;
      while (__hip_atomic_load(root + (size_t)t * 16, __ATOMIC_RELAXED,
                               __HIP_MEMORY_SCOPE_AGENT) < 16u) {
        __builtin_amdgcn_s_sleep(1);
        if (++guard > (1 << 22)) break;   // bounded: fail loud, never hang
      }
    }
    __syncthreads();
  }

  if (tid < 128) cbuf[(size_t)bq * H_ + J0 + jq] = cstate;
}

// ---------------- host ----------------
extern "C" void kernel_launch(void* const* d_in, const int* in_sizes, int n_in,
                              void* d_out, int out_size, void* d_ws, size_t ws_size,
                              hipStream_t stream) {
  const int*   src = (const int*)d_in[0];
  const float* emb = (const float*)d_in[1];
  const float* Wih = (const float*)d_in[2];
  const float* Whh = (const float*)d_in[3];
  const float* bih = (const float*)d_in[4];
  const float* bhh = (const float*)d_in[5];
  float* out = (float*)d_out;

  // ws: [cbuf 128K][root 32K][grp 512K][Wt 8M][hring (chunk+1)*64K][xg chunk*512K]
  char* ws = (char*)d_ws;
  float*     cbuf = (float*)ws;                        // 131072
  unsigned*  root = (unsigned*)(ws + 131072);          // 32768
  unsigned*  grp  = (unsigned*)(ws + 131072 + 32768);  // 524288
  const size_t stateBytes = 131072 + 32768 + 524288;   // 688128
  _Float16*  Wt   = (_Float16*)(ws + stateBytes);      // 8 MB
  const size_t wtBytes = (size_t)G_ * H_ * 2;          // 8388608

  int chunk = 0;
  const int cand[4] = {256, 128, 64, 32};
  for (int ci = 0; ci < 4; ++ci) {
    size_t need = stateBytes + wtBytes + (size_t)(cand[ci] + 1) * (BH_ * 2)
                  + (size_t)cand[ci] * B_ * G_ * 4;
    if (need <= ws_size) { chunk = cand[ci]; break; }
  }
  if (chunk == 0) return;  // fail loud

  unsigned short* hring = (unsigned short*)(ws + stateBytes + wtBytes);
  float* xg = (float*)(ws + stateBytes + wtBytes + (size_t)(chunk + 1) * (BH_ * 2));

  (void)hipMemsetAsync(ws, 0, stateBytes, stream);   // c0 = 0, all counters = 0
  (void)hipMemsetAsync(hring, 0, BH_ * 2, stream);   // h0 = 0 (ring slot 0)

  wt_kernel<<<dim3(64, 16), 256, 0, stream>>>(Whh, Wt);

  for (int t0 = 0; t0 < S_; t0 += chunk) {
    dim3 ga(G_ / 128, (chunk * B_) / 128);
    xgates_gemm<<<ga, 256, 0, stream>>>(src, emb, Wih, bih, bhh, xg, t0);

    int nt = chunk;
    void* args[] = {(void*)&Wt, (void*)&xg, (void*)&hring, (void*)&cbuf,
                    (void*)&root, (void*)&grp, (void*)&out, (void*)&t0, (void*)&nt};
    (void)hipLaunchCooperativeKernel((void*)lstm_mfma, dim3(NWG), dim3(RTHR),
                                     args, 0u, stream);
  }
}